// Round 1
// baseline (2218.189 us; speedup 1.0000x reference)
//
#include <hip/hip_runtime.h>

// Problem constants (fixed by reference)
#define NU 100000
#define NI 50000
#define NN 150000          // NU + NI
#define DIM 128
#define NHOPS 3
#define STR ((NHOPS + 1) * DIM)   // 512 floats per node in d_out: [hop0..hop3][128]

// ---------------- CSR build ----------------

__global__ void hist_kernel(const int* __restrict__ rows, int* deg, int E) {
  int i = blockIdx.x * blockDim.x + threadIdx.x;
  int stride = gridDim.x * blockDim.x;
  for (; i < E; i += stride) atomicAdd(&deg[rows[i]], 1);
}

// Single-block exclusive scan over n=150000 degrees.
// deg_cursor: in = degrees, out = row starts (used as scatter cursor).
// row_start: row starts, plus row_start[n] = total.
__global__ void scan_kernel(int* deg_cursor, int* row_start, int n, int total) {
  __shared__ int sums[1024];
  int t = threadIdx.x;
  int chunk = (n + 1023) >> 10;
  int beg = t * chunk;
  int end = beg + chunk; if (end > n) end = n;
  int s = 0;
  for (int i = beg; i < end; ++i) s += deg_cursor[i];
  sums[t] = s;
  __syncthreads();
  for (int off = 1; off < 1024; off <<= 1) {
    int v = (t >= off) ? sums[t - off] : 0;
    __syncthreads();
    sums[t] += v;
    __syncthreads();
  }
  int run = sums[t] - s;  // exclusive prefix of this thread's chunk
  for (int i = beg; i < end; ++i) {
    int d = deg_cursor[i];       // read before overwrite (same thread, ordered)
    row_start[i] = run;
    deg_cursor[i] = run;
    run += d;
  }
  if (t == 0) row_start[n] = total;
}

__global__ void scatter_kernel(const int* __restrict__ rows, const int* __restrict__ cols,
                               const float* __restrict__ vals, int* cursor,
                               int* __restrict__ csr_col, float* __restrict__ csr_val, int E) {
  int i = blockIdx.x * blockDim.x + threadIdx.x;
  int stride = gridDim.x * blockDim.x;
  for (; i < E; i += stride) {
    int r = rows[i];
    int p = atomicAdd(&cursor[r], 1);
    csr_col[p] = cols[i];
    csr_val[p] = vals[i];
  }
}

// ---------------- dense kernels ----------------

// Write raw concat(user_embed, item_embed) into hop-slot 0 of d_out.
__global__ void copy_embed_kernel(const float* __restrict__ ue, const float* __restrict__ ie,
                                  float* __restrict__ out) {
  int idx = blockIdx.x * blockDim.x + threadIdx.x;  // float4 index, total NN*DIM/4
  if (idx >= NN * (DIM / 4)) return;
  int node = idx >> 5;   // DIM/4 == 32 float4 per node
  int d4 = idx & 31;
  const float4* src = (node < NU)
      ? ((const float4*)(ue + (size_t)node * DIM) + d4)
      : ((const float4*)(ie + (size_t)(node - NU) * DIM) + d4);
  ((float4*)(out + (size_t)node * STR))[d4] = *src;
}

// One wave (64 lanes) per row; lane owns 2 of the 128 dims.
// Reads hop-slot kin of `base`, writes raw side into hop-slot kout.
__global__ void spmm_kernel(const int* __restrict__ row_start, const int* __restrict__ csr_col,
                            const float* __restrict__ csr_val, const float* base_in,
                            float* base_out, int kin_off, int kout_off) {
  int wave = (blockIdx.x * blockDim.x + threadIdx.x) >> 6;
  if (wave >= NN) return;   // wave-uniform exit (row per wave)
  int lane = threadIdx.x & 63;
  int s = row_start[wave];
  int e = row_start[wave + 1];
  float ax = 0.f, ay = 0.f;
  const float* src_base = base_in + kin_off + lane * 2;
  int p = s;
  for (; p + 8 <= e; p += 8) {
    // lanes 0..7 hold the 8 edges; replicate via &7 so every lane has a valid load
    int c = csr_col[p + (lane & 7)];
    float v = csr_val[p + (lane & 7)];
#pragma unroll
    for (int j = 0; j < 8; ++j) {
      int cc = __shfl(c, j);
      float vv = __shfl(v, j);
      float2 x = *(const float2*)(src_base + (size_t)cc * STR);
      ax += vv * x.x;
      ay += vv * x.y;
    }
  }
  for (; p < e; ++p) {
    int cc = csr_col[p];
    float vv = csr_val[p];
    float2 x = *(const float2*)(src_base + (size_t)cc * STR);
    ax += vv * x.x;
    ay += vv * x.y;
  }
  float2 o; o.x = ax; o.y = ay;
  *(float2*)(base_out + (size_t)wave * STR + kout_off + lane * 2) = o;
}

// Fallback (ws too small): edge-parallel atomics, one wave per edge.
__global__ void spmm_atomic_kernel(const int* __restrict__ rows, const int* __restrict__ cols,
                                   const float* __restrict__ vals, const float* base_in,
                                   float* base_out, int kin_off, int kout_off, int E) {
  int wave = (blockIdx.x * blockDim.x + threadIdx.x) >> 6;
  if (wave >= E) return;
  int lane = threadIdx.x & 63;
  int r = rows[wave], c = cols[wave];
  float v = vals[wave];
  float2 x = *(const float2*)(base_in + (size_t)c * STR + kin_off + lane * 2);
  float* dst = base_out + (size_t)r * STR + kout_off + lane * 2;
  atomicAdd(dst, v * x.x);
  atomicAdd(dst + 1, v * x.y);
}

// Scale hop-slot k by t*(1-t)^k (k=0 -> t) in place.
__global__ void epilogue_kernel(const float* __restrict__ ut, const float* __restrict__ it,
                                float* __restrict__ out) {
  int idx = blockIdx.x * blockDim.x + threadIdx.x;  // float4 units, total NN*STR/4
  if (idx >= NN * (STR / 4)) return;
  int node = idx >> 7;     // STR/4 == 128 float4 per node
  int rem = idx & 127;
  int k = rem >> 5;        // 32 float4 per hop slot
  float t = (node < NU) ? ut[node] : it[node - NU];
  float dcy = 1.f - t;
  float sc = t;
  for (int j = 0; j < k; ++j) sc *= dcy;
  float4* p = (float4*)out + idx;
  float4 x = *p;
  x.x *= sc; x.y *= sc; x.z *= sc; x.w *= sc;
  *p = x;
}

// ---------------- launch ----------------

extern "C" void kernel_launch(void* const* d_in, const int* in_sizes, int n_in,
                              void* d_out, int out_size, void* d_ws, size_t ws_size,
                              hipStream_t stream) {
  const float* ue = (const float*)d_in[0];
  const float* ie = (const float*)d_in[1];
  const float* ut = (const float*)d_in[2];
  const float* it = (const float*)d_in[3];
  const float* vals = (const float*)d_in[4];
  const int* rows = (const int*)d_in[5];
  const int* cols = (const int*)d_in[6];
  float* out = (float*)d_out;
  const int E = in_sizes[4];

  // workspace layout (256B-aligned slabs)
  size_t off = 0;
  auto alloc = [&](size_t bytes) {
    void* p = (char*)d_ws + off;
    off += (bytes + 255) & ~(size_t)255;
    return p;
  };
  int* cursor = (int*)alloc((size_t)NN * 4);
  int* rstart = (int*)alloc(((size_t)NN + 1) * 4);
  int* csr_col = (int*)alloc((size_t)E * 4);
  float* csr_val = (float*)alloc((size_t)E * 4);
  bool use_csr = (off <= ws_size);

  const int n4_embed = NN * (DIM / 4);

  if (use_csr) {
    // slot 0 <- raw embeddings (hop-1 gather source)
    copy_embed_kernel<<<(n4_embed + 255) / 256, 256, 0, stream>>>(ue, ie, out);
    // CSR build
    hipMemsetAsync(cursor, 0, (size_t)NN * 4, stream);
    hist_kernel<<<2048, 256, 0, stream>>>(rows, cursor, E);
    scan_kernel<<<1, 1024, 0, stream>>>(cursor, rstart, NN, E);
    scatter_kernel<<<2048, 256, 0, stream>>>(rows, cols, vals, cursor, csr_col, csr_val, E);
    // 3 hops: slot(h-1) -> slot(h), raw (unscaled) sides
    for (int h = 1; h <= NHOPS; ++h) {
      spmm_kernel<<<(NN + 3) / 4, 256, 0, stream>>>(rstart, csr_col, csr_val, out, out,
                                                    (h - 1) * DIM, h * DIM);
    }
  } else {
    // fallback: zero everything, copy slot 0, atomic edge-parallel SpMM
    hipMemsetAsync(out, 0, (size_t)out_size * 4, stream);
    copy_embed_kernel<<<(n4_embed + 255) / 256, 256, 0, stream>>>(ue, ie, out);
    for (int h = 1; h <= NHOPS; ++h) {
      long threads = (long)E * 64;
      spmm_atomic_kernel<<<(threads + 255) / 256, 256, 0, stream>>>(rows, cols, vals, out, out,
                                                                    (h - 1) * DIM, h * DIM, E);
    }
  }

  // scale all hop slots in place
  const int n4_out = NN * (STR / 4);
  epilogue_kernel<<<(n4_out + 255) / 256, 256, 0, stream>>>(ut, it, out);
}

// Round 2
// 1935.780 us; speedup vs baseline: 1.1459x; 1.1459x over previous
//
#include <hip/hip_runtime.h>

// Problem constants (fixed by reference)
#define NU 100000
#define NI 50000
#define NN 150000          // NU + NI
#define DIM 128
#define NHOPS 3
#define STR ((NHOPS + 1) * DIM)   // 512 floats per node in d_out

// ---------------- CSR build ----------------

__global__ void hist_kernel(const int* __restrict__ rows, int* deg, int E) {
  int i = blockIdx.x * blockDim.x + threadIdx.x;
  int stride = gridDim.x * blockDim.x;
  for (; i < E; i += stride) atomicAdd(&deg[rows[i]], 1);
}

// 3-kernel multi-block exclusive scan over NN degrees.
// k1: per-block (2048-elem) sums.  k2: serial scan of ~74 block sums.
// k3: local scan + block offset -> rstart & cursor.
__global__ void scan_k1(const int* __restrict__ deg, int* bsum, int n) {
  __shared__ int red[256];
  int b = blockIdx.x, t = threadIdx.x;
  int base = b * 2048 + t * 8;
  int s = 0;
#pragma unroll
  for (int j = 0; j < 8; ++j) { int i = base + j; if (i < n) s += deg[i]; }
  red[t] = s;
  __syncthreads();
  for (int off = 128; off > 0; off >>= 1) {
    if (t < off) red[t] += red[t + off];
    __syncthreads();
  }
  if (t == 0) bsum[b] = red[0];
}

__global__ void scan_k2(int* bsum, int nb) {
  if (threadIdx.x == 0) {
    int run = 0;
    for (int i = 0; i < nb; ++i) { int v = bsum[i]; bsum[i] = run; run += v; }
  }
}

__global__ void scan_k3(const int* __restrict__ deg, const int* __restrict__ bsum,
                        int* __restrict__ rstart, int* __restrict__ cursor, int n, int E) {
  __shared__ int red[256];
  int b = blockIdx.x, t = threadIdx.x;
  int base = b * 2048 + t * 8;
  int loc[8];
  int s = 0;
#pragma unroll
  for (int j = 0; j < 8; ++j) {
    int i = base + j;
    int d = (i < n) ? deg[i] : 0;
    loc[j] = s; s += d;
  }
  red[t] = s;
  __syncthreads();
  for (int off = 1; off < 256; off <<= 1) {
    int v = (t >= off) ? red[t - off] : 0;
    __syncthreads();
    red[t] += v;
    __syncthreads();
  }
  int toff = bsum[b] + red[t] - s;  // exclusive prefix for this thread
#pragma unroll
  for (int j = 0; j < 8; ++j) {
    int i = base + j;
    if (i < n) { int v = toff + loc[j]; rstart[i] = v; cursor[i] = v; }
  }
  if (b == 0 && t == 0) rstart[n] = E;
}

// Interleaved 8B CSR entry: .x = col, .y = val bits. One store per edge.
__global__ void scatter_kernel(const int* __restrict__ rows, const int* __restrict__ cols,
                               const float* __restrict__ vals, int* cursor,
                               int2* __restrict__ csr, int E) {
  int i = blockIdx.x * blockDim.x + threadIdx.x;
  int stride = gridDim.x * blockDim.x;
  for (; i < E; i += stride) {
    int r = rows[i];
    int p = atomicAdd(&cursor[r], 1);
    int2 e; e.x = cols[i]; e.y = __float_as_int(vals[i]);
    csr[p] = e;
  }
}

// ---------------- dense kernels ----------------

// raw concat -> rawA (stride DIM, compact); scaled ego (t*embed) -> out slot 0.
__global__ void copy_embed_fused(const float* __restrict__ ue, const float* __restrict__ ie,
                                 const float* __restrict__ ut, const float* __restrict__ it,
                                 float* __restrict__ rawA, float* __restrict__ out) {
  int idx = blockIdx.x * blockDim.x + threadIdx.x;  // float4 index, NN*DIM/4 total
  if (idx >= NN * (DIM / 4)) return;
  int node = idx >> 5;   // 32 float4 per node
  int d4 = idx & 31;
  float t;
  float4 x;
  if (node < NU) { t = ut[node]; x = ((const float4*)(ue + (size_t)node * DIM))[d4]; }
  else { t = it[node - NU]; x = ((const float4*)(ie + (size_t)(node - NU) * DIM))[d4]; }
  ((float4*)(rawA + (size_t)node * DIM))[d4] = x;
  float4 y; y.x = x.x * t; y.y = x.y * t; y.z = x.z * t; y.w = x.w * t;
  ((float4*)(out + (size_t)node * STR))[d4] = y;
}

// Fallback: raw concat -> out slot 0 only (epilogue scales later).
__global__ void copy_embed_raw(const float* __restrict__ ue, const float* __restrict__ ie,
                               float* __restrict__ out) {
  int idx = blockIdx.x * blockDim.x + threadIdx.x;
  if (idx >= NN * (DIM / 4)) return;
  int node = idx >> 5;
  int d4 = idx & 31;
  const float4* src = (node < NU)
      ? ((const float4*)(ue + (size_t)node * DIM) + d4)
      : ((const float4*)(ie + (size_t)(node - NU) * DIM) + d4);
  ((float4*)(out + (size_t)node * STR))[d4] = *src;
}

// One wave per row; lane owns 2 dims. Gathers from src (stride src_str),
// optionally writes raw side (raw_out) and/or scaled side (scaled_out).
__global__ void spmm_kernel(const int* __restrict__ row_start, const int2* __restrict__ csr,
                            const float* __restrict__ src, int src_str,
                            float* raw_out, int raw_str,
                            float* scaled_out, int scaled_str,
                            const float* __restrict__ ut, const float* __restrict__ it, int hop) {
  int wave = (blockIdx.x * blockDim.x + threadIdx.x) >> 6;
  if (wave >= NN) return;   // wave-uniform exit
  int lane = threadIdx.x & 63;
  int s = row_start[wave];
  int e = row_start[wave + 1];
  float ax = 0.f, ay = 0.f;
  const float* src_base = src + lane * 2;
  int p = s;
  for (; p + 8 <= e; p += 8) {
    int2 ed = csr[p + (lane & 7)];
#pragma unroll
    for (int j = 0; j < 8; ++j) {
      int cc = __shfl(ed.x, j);
      float vv = __int_as_float(__shfl(ed.y, j));
      float2 x = *(const float2*)(src_base + (size_t)cc * src_str);
      ax += vv * x.x;
      ay += vv * x.y;
    }
  }
  for (; p < e; ++p) {
    int2 ed = csr[p];
    float2 x = *(const float2*)(src_base + (size_t)ed.x * src_str);
    float vv = __int_as_float(ed.y);
    ax += vv * x.x;
    ay += vv * x.y;
  }
  if (raw_out) {
    float2 o; o.x = ax; o.y = ay;
    *(float2*)(raw_out + (size_t)wave * raw_str + lane * 2) = o;
  }
  if (scaled_out) {
    float t = (wave < NU) ? ut[wave] : it[wave - NU];
    float sc = t;
    for (int j = 0; j < hop; ++j) sc *= (1.f - t);
    float2 o; o.x = ax * sc; o.y = ay * sc;
    *(float2*)(scaled_out + (size_t)wave * scaled_str + lane * 2) = o;
  }
}

// Fallback epilogue: scale slots 0..2 in place by t*(1-t)^k.
__global__ void epilogue_kernel(const float* __restrict__ ut, const float* __restrict__ it,
                                float* __restrict__ out) {
  int idx = blockIdx.x * blockDim.x + threadIdx.x;  // float4 units, NN * 96 total
  if (idx >= NN * 96) return;
  int node = idx / 96;
  int rem = idx - node * 96;
  int k = rem >> 5;        // slot 0..2
  int d4 = rem & 31;
  float t = (node < NU) ? ut[node] : it[node - NU];
  float dcy = 1.f - t;
  float sc = t;
  for (int j = 0; j < k; ++j) sc *= dcy;
  float4* p = (float4*)(out + (size_t)node * STR + k * DIM) + d4;
  float4 x = *p;
  x.x *= sc; x.y *= sc; x.z *= sc; x.w *= sc;
  *p = x;
}

// ---------------- launch ----------------

extern "C" void kernel_launch(void* const* d_in, const int* in_sizes, int n_in,
                              void* d_out, int out_size, void* d_ws, size_t ws_size,
                              hipStream_t stream) {
  const float* ue = (const float*)d_in[0];
  const float* ie = (const float*)d_in[1];
  const float* ut = (const float*)d_in[2];
  const float* it = (const float*)d_in[3];
  const float* vals = (const float*)d_in[4];
  const int* rows = (const int*)d_in[5];
  const int* cols = (const int*)d_in[6];
  float* out = (float*)d_out;
  const int E = in_sizes[4];

  size_t off = 0;
  auto alloc = [&](size_t bytes) {
    void* p = (char*)d_ws + off;
    off += (bytes + 255) & ~(size_t)255;
    return p;
  };
  int* deg = (int*)alloc((size_t)NN * 4);
  int* cursor = (int*)alloc((size_t)NN * 4);
  int* rstart = (int*)alloc(((size_t)NN + 1) * 4);
  int* bsum = (int*)alloc(1024 * 4);
  int2* csr = (int2*)alloc((size_t)E * 8);
  size_t csr_end = off;
  float* rawA = (float*)alloc((size_t)NN * DIM * 4);
  float* rawB = (float*)alloc((size_t)NN * DIM * 4);
  bool use_csr = (csr_end <= ws_size);
  bool use_compact = (off <= ws_size);

  const int n4_embed = NN * (DIM / 4);
  const int nb_scan = (NN + 2047) / 2048;
  const int spmm_blocks = (NN + 3) / 4;   // 4 waves/block, 1 wave/row

  if (use_csr) {
    // ---- CSR build ----
    hipMemsetAsync(deg, 0, (size_t)NN * 4, stream);
    hist_kernel<<<2048, 256, 0, stream>>>(rows, deg, E);
    scan_k1<<<nb_scan, 256, 0, stream>>>(deg, bsum, NN);
    scan_k2<<<1, 64, 0, stream>>>(bsum, nb_scan);
    scan_k3<<<nb_scan, 256, 0, stream>>>(deg, bsum, rstart, cursor, NN, E);
    scatter_kernel<<<2048, 256, 0, stream>>>(rows, cols, vals, cursor, csr, E);

    if (use_compact) {
      // primary path: compact raw ping-pong in ws, scaled writes fused
      copy_embed_fused<<<(n4_embed + 255) / 256, 256, 0, stream>>>(ue, ie, ut, it, rawA, out);
      float* rin = rawA;
      float* rout = rawB;
      for (int h = 1; h <= NHOPS; ++h) {
        float* raw_dst = (h < NHOPS) ? rout : nullptr;  // last hop: no raw consumer
        spmm_kernel<<<spmm_blocks, 256, 0, stream>>>(rstart, csr, rin, DIM,
                                                     raw_dst, DIM,
                                                     out + h * DIM, STR, ut, it, h);
        float* tmp = rin; rin = rout; rout = tmp;
      }
    } else {
      // fallback: raw slots in d_out, epilogue scales slots 0..2
      copy_embed_raw<<<(n4_embed + 255) / 256, 256, 0, stream>>>(ue, ie, out);
      for (int h = 1; h <= NHOPS; ++h) {
        float* raw_dst = (h < NHOPS) ? (out + h * DIM) : nullptr;
        float* sc_dst = (h == NHOPS) ? (out + h * DIM) : nullptr;
        spmm_kernel<<<spmm_blocks, 256, 0, stream>>>(rstart, csr, out + (h - 1) * DIM, STR,
                                                     raw_dst, STR, sc_dst, STR, ut, it, h);
      }
      epilogue_kernel<<<(NN * 96 + 255) / 256, 256, 0, stream>>>(ut, it, out);
    }
  }
  // (no atomic fallback: harness guarantees a usable ws; CSR needs only ~40MB)
}